// Round 9
// baseline (1091.471 us; speedup 1.0000x reference)
//
#include <hip/hip_runtime.h>

typedef __attribute__((ext_vector_type(8))) short short8;
typedef __attribute__((ext_vector_type(4))) float f32x4;

#define SS 1024
#define HR 72    // hbuf row stride in shorts (144 B, 16B-aligned rows)

__device__ __forceinline__ float sigmoidf_(float x) {
    return __builtin_amdgcn_rcpf(1.0f + __expf(-x));
}
__device__ __forceinline__ float tanhf_(float x) {
    return 1.0f - 2.0f * __builtin_amdgcn_rcpf(__expf(2.0f * x) + 1.0f);
}
__device__ __forceinline__ unsigned short f2bf(float f) {   // RNE f32->bf16
    unsigned int u = __float_as_uint(f);
    u += 0x7fffu + ((u >> 16) & 1u);
    return (unsigned short)(u >> 16);
}
__device__ __forceinline__ float bf2f(unsigned short s) {
    return __uint_as_float(((unsigned int)s) << 16);
}

#define MF(A, B, C) __builtin_amdgcn_mfma_f32_16x16x32_bf16(A, B, C, 0, 0, 0)
// lgkm-only barrier: global (vmcnt) prefetches stay in flight across it.
#define RAW_BARRIER() asm volatile("s_waitcnt lgkmcnt(0)\n\ts_barrier" ::: "memory")

// B-fragment loader: lane (m=l&15, q=l>>4) holds B[k=kbase+j][col], j=0..7.
__device__ __forceinline__ short8 loadBfrag(const float* __restrict__ W,
                                            int kbase, int col) {
    short8 v;
#pragma unroll
    for (int j = 0; j < 8; ++j) v[j] = (short)f2bf(W[(kbase + j) * 256 + col]);
    return v;
}

// ========== Kernel 1: z_x = x @ Wx + bias, C-layout output ==========
// Output zx[b>>2][t][gatecol 256][4 batch rows] f32 — so the rec kernel's
// MFMA C-init is ONE f32x4 load. Full-chip GEMM: 256 blocks; block =
// (batch-tile 16) x (t-chunk 64); wave w owns gatecols [64w, 64w+64).
__global__ __launch_bounds__(256, 1)
void xz_mfma(const float* __restrict__ x, const float* __restrict__ wk,
             const float* __restrict__ bias, float* __restrict__ zx) {
    const int tid = threadIdx.x;
    const int l = tid & 63, w = tid >> 6;
    const int m = l & 15, q = l >> 4;
    const int bt = blockIdx.x >> 4;          // batch tile (16 rows)
    const int t0 = (blockIdx.x & 15) << 6;   // t chunk (64 steps)

    const int gc0 = w * 64 + m;              // D col for nt=0; +16 per nt
    const short8 B0a = loadBfrag(wk, q * 8,      gc0);
    const short8 B0b = loadBfrag(wk, 32 + q * 8, gc0);
    const short8 B1a = loadBfrag(wk, q * 8,      gc0 + 16);
    const short8 B1b = loadBfrag(wk, 32 + q * 8, gc0 + 16);
    const short8 B2a = loadBfrag(wk, q * 8,      gc0 + 32);
    const short8 B2b = loadBfrag(wk, 32 + q * 8, gc0 + 32);
    const short8 B3a = loadBfrag(wk, q * 8,      gc0 + 48);
    const short8 B3b = loadBfrag(wk, 32 + q * 8, gc0 + 48);
    const float bv0 = bias[gc0],      bv1 = bias[gc0 + 16];
    const float bv2 = bias[gc0 + 32], bv3 = bias[gc0 + 48];
    const f32x4 cb0 = {bv0, bv0, bv0, bv0};
    const f32x4 cb1 = {bv1, bv1, bv1, bv1};
    const f32x4 cb2 = {bv2, bv2, bv2, bv2};
    const f32x4 cb3 = {bv3, bv3, bv3, bv3};

    const float* __restrict__ xb = x + ((size_t)(bt * 16 + m) * SS) * 64;
    float4 p0, p1, p2, p3;
    {
        const float* xr = xb + (size_t)t0 * 64;
        p0 = *(const float4*)(xr + q * 8);
        p1 = *(const float4*)(xr + q * 8 + 4);
        p2 = *(const float4*)(xr + 32 + q * 8);
        p3 = *(const float4*)(xr + 32 + q * 8 + 4);
    }
    f32x4* __restrict__ zp = (f32x4*)zx;

    for (int tt = 0; tt < 64; ++tt) {
        const int t = t0 + tt;
        const float4 c0 = p0, c1 = p1, c2 = p2, c3 = p3;
        if (tt < 63) {                       // prefetch next t row
            const float* xr = xb + (size_t)(t + 1) * 64;
            p0 = *(const float4*)(xr + q * 8);
            p1 = *(const float4*)(xr + q * 8 + 4);
            p2 = *(const float4*)(xr + 32 + q * 8);
            p3 = *(const float4*)(xr + 32 + q * 8 + 4);
        }
        short8 a0, a1;                       // A-frag: row m, k = q*8+j (+32)
        a0[0] = (short)f2bf(c0.x); a0[1] = (short)f2bf(c0.y);
        a0[2] = (short)f2bf(c0.z); a0[3] = (short)f2bf(c0.w);
        a0[4] = (short)f2bf(c1.x); a0[5] = (short)f2bf(c1.y);
        a0[6] = (short)f2bf(c1.z); a0[7] = (short)f2bf(c1.w);
        a1[0] = (short)f2bf(c2.x); a1[1] = (short)f2bf(c2.y);
        a1[2] = (short)f2bf(c2.z); a1[3] = (short)f2bf(c2.w);
        a1[4] = (short)f2bf(c3.x); a1[5] = (short)f2bf(c3.y);
        a1[6] = (short)f2bf(c3.z); a1[7] = (short)f2bf(c3.w);

        // D rows = q*4+r -> batch block bt*4+q, rows 0..3 -> f32x4 store
        const size_t ob = ((size_t)(bt * 4 + q) * SS + t) * 256;
        f32x4 d;
        d = MF(a1, B0b, MF(a0, B0a, cb0)); zp[ob + gc0]      = d;
        d = MF(a1, B1b, MF(a0, B1a, cb1)); zp[ob + gc0 + 16] = d;
        d = MF(a1, B2b, MF(a0, B2a, cb2)); zp[ob + gc0 + 32] = d;
        d = MF(a1, B3b, MF(a0, B3a, cb3)); zp[ob + gc0 + 48] = d;
    }
}

// ========== Kernel 2: recurrence, M=4 batch rows/block, 64 blocks ==========
// Per step: ha (2x b128 LDS) -> 8 MFMAs (C = prefetched zx f32x4) -> gates
// computed IN C-LAYOUT on q==0 lanes (rows 0-3 all live there; no z LDS
// round-trip, no producer/consumer split) -> h written as 4 b16 to hbuf.
// ONE lgkm-only barrier per step. Wave 3 additionally emits the dense+sigmoid
// output for the previous step from hbuf.

#define DENSE(PR, TOUT) {                                                     \
    const int r = l >> 4, j4 = (l & 15) << 2;                                 \
    const uint2 hh = *(const uint2*)&hbuf[PR][r * HR + j4];                   \
    float pd = bf2f((unsigned short)hh.x)         * dwv.x                     \
             + bf2f((unsigned short)(hh.x >> 16)) * dwv.y                     \
             + bf2f((unsigned short)hh.y)         * dwv.z                     \
             + bf2f((unsigned short)(hh.y >> 16)) * dwv.w;                    \
    pd += __shfl_xor(pd, 1, 64); pd += __shfl_xor(pd, 2, 64);                 \
    pd += __shfl_xor(pd, 4, 64); pd += __shfl_xor(pd, 8, 64);                 \
    if ((l & 15) == 0)                                                        \
        out[((size_t)((bb << 2) + r) << 10) + (TOUT)] = sigmoidf_(pd + db0);  \
}

#define STEP(T, Si, Sf, Sc, So) do {                                          \
    const int p = (T) & 1, pr = p ^ 1;                                        \
    RAW_BARRIER();                                                            \
    if (w == 3 && (T) > 0) { DENSE(pr, (T) - 1); }                            \
    const short8 ha0 = *(const short8*)&hbuf[pr][m * HR + (q << 3)];          \
    const short8 ha1 = *(const short8*)&hbuf[pr][m * HR + 32 + (q << 3)];     \
    const f32x4 ci = (q == 0) ? Si : z4;                                      \
    const f32x4 cf = (q == 0) ? Sf : z4;                                      \
    const f32x4 cz = (q == 0) ? Sc : z4;                                      \
    const f32x4 co = (q == 0) ? So : z4;                                      \
    const f32x4 zi = MF(ha1, H0b, MF(ha0, H0a, ci));                          \
    const f32x4 zf = MF(ha1, H1b, MF(ha0, H1a, cf));                          \
    const f32x4 zc = MF(ha1, H2b, MF(ha0, H2a, cz));                          \
    const f32x4 zo = MF(ha1, H3b, MF(ha0, H3a, co));                          \
    if (q == 0) {                                                             \
        {   /* refill this slot for T+4 (~1400 cy ahead, crosses barriers) */ \
            const int tn = ((T) + 4 < SS) ? (T) + 4 : SS - 1;                 \
            const f32x4* zpt = zp + (size_t)tn * 256;                         \
            Si = zpt[0]; Sf = zpt[64]; Sc = zpt[128]; So = zpt[192];          \
        }                                                                     \
        float hv0, hv1, hv2, hv3;                                             \
        { const float ig = sigmoidf_(zi[0]), fg = sigmoidf_(zf[0]),           \
                      og = sigmoidf_(zo[0]);                                  \
          cc[0] = fg * cc[0] + ig * tanhf_(zc[0]); hv0 = og * tanhf_(cc[0]); }\
        { const float ig = sigmoidf_(zi[1]), fg = sigmoidf_(zf[1]),           \
                      og = sigmoidf_(zo[1]);                                  \
          cc[1] = fg * cc[1] + ig * tanhf_(zc[1]); hv1 = og * tanhf_(cc[1]); }\
        { const float ig = sigmoidf_(zi[2]), fg = sigmoidf_(zf[2]),           \
                      og = sigmoidf_(zo[2]);                                  \
          cc[2] = fg * cc[2] + ig * tanhf_(zc[2]); hv2 = og * tanhf_(cc[2]); }\
        { const float ig = sigmoidf_(zi[3]), fg = sigmoidf_(zf[3]),           \
                      og = sigmoidf_(zo[3]);                                  \
          cc[3] = fg * cc[3] + ig * tanhf_(zc[3]); hv3 = og * tanhf_(cc[3]); }\
        hbuf[p][0 * HR + gn] = f2bf(hv0);                                     \
        hbuf[p][1 * HR + gn] = f2bf(hv1);                                     \
        hbuf[p][2 * HR + gn] = f2bf(hv2);                                     \
        hbuf[p][3 * HR + gn] = f2bf(hv3);                                     \
    }                                                                         \
} while (0)

__global__ __launch_bounds__(256, 1)
void lstm_rec(const float* __restrict__ zx, const float* __restrict__ rk,
              const float* __restrict__ dw, const float* __restrict__ db,
              float* __restrict__ out) {
    const int tid = threadIdx.x;
    const int l = tid & 63, w = tid >> 6;
    const int m = l & 15, q = l >> 4;
    const int bb = blockIdx.x;               // batch rows bb*4 .. bb*4+3
    const int gn = w * 16 + m;               // h column owned by this lane

    // 8 recurrent-weight B-frags (register-resident by construction)
    const short8 H0a = loadBfrag(rk, q * 8,      0 * 64 + gn);
    const short8 H0b = loadBfrag(rk, 32 + q * 8, 0 * 64 + gn);
    const short8 H1a = loadBfrag(rk, q * 8,      1 * 64 + gn);
    const short8 H1b = loadBfrag(rk, 32 + q * 8, 1 * 64 + gn);
    const short8 H2a = loadBfrag(rk, q * 8,      2 * 64 + gn);
    const short8 H2b = loadBfrag(rk, 32 + q * 8, 2 * 64 + gn);
    const short8 H3a = loadBfrag(rk, q * 8,      3 * 64 + gn);
    const short8 H3b = loadBfrag(rk, 32 + q * 8, 3 * 64 + gn);

    __shared__ __align__(16) unsigned short hbuf[2][16 * HR];
    for (int i = tid; i < 2 * 16 * HR; i += 256) ((unsigned short*)hbuf)[i] = 0;

    float4 dwv = {0.f, 0.f, 0.f, 0.f};
    if (w == 3) dwv = *(const float4*)(dw + (l & 15) * 4);
    const float db0 = db[0];

    const f32x4* __restrict__ zp =
        (const f32x4*)zx + (size_t)bb * SS * 256 + gn;

    f32x4 cc = {0.f, 0.f, 0.f, 0.f};
    const f32x4 z4 = {0.f, 0.f, 0.f, 0.f};

    // 4-deep rotating zx prefetch (q==0 lanes), slots for t=0..3
    f32x4 Ai = z4, Af = z4, Ac = z4, Ao = z4;
    f32x4 Bi = z4, Bf = z4, Bc = z4, Bo = z4;
    f32x4 Ci = z4, Cf = z4, Cc = z4, Co = z4;
    f32x4 Di = z4, Df = z4, Dc = z4, Do = z4;
    if (q == 0) {
        const f32x4* zt;
        zt = zp + 0 * 256; Ai = zt[0]; Af = zt[64]; Ac = zt[128]; Ao = zt[192];
        zt = zp + 1 * 256; Bi = zt[0]; Bf = zt[64]; Bc = zt[128]; Bo = zt[192];
        zt = zp + 2 * 256; Ci = zt[0]; Cf = zt[64]; Cc = zt[128]; Co = zt[192];
        zt = zp + 3 * 256; Di = zt[0]; Df = zt[64]; Dc = zt[128]; Do = zt[192];
    }
    __syncthreads();

    for (int t = 0; t < SS; t += 4) {
        STEP(t,     Ai, Af, Ac, Ao);
        STEP(t + 1, Bi, Bf, Bc, Bo);
        STEP(t + 2, Ci, Cf, Cc, Co);
        STEP(t + 3, Di, Df, Dc, Do);
    }
    RAW_BARRIER();
    if (w == 3) { DENSE(1, SS - 1); }        // h_{1023} lives in hbuf[1]
}

// ========== Host ==========
extern "C" void kernel_launch(void* const* d_in, const int* in_sizes, int n_in,
                              void* d_out, int out_size, void* d_ws, size_t ws_size,
                              hipStream_t stream) {
    const float* x    = (const float*)d_in[0];
    const float* wk   = (const float*)d_in[1];
    const float* rk   = (const float*)d_in[2];
    const float* bias = (const float*)d_in[3];
    const float* dw   = (const float*)d_in[4];
    const float* db   = (const float*)d_in[5];
    float* out = (float*)d_out;

    // zx: [64][1024][256][4] f32 = 268,435,456 B.
    // ws >= 268,566,528 B proven by round 6 (cs=1024 path ran).
    float* zx = (float*)d_ws;

    hipLaunchKernelGGL(xz_mfma, dim3(256), dim3(256), 0, stream,
                       x, wk, bias, zx);
    hipLaunchKernelGGL(lstm_rec, dim3(64), dim3(256), 0, stream,
                       zx, rk, dw, db, out);
}